// Round 7
// baseline (267.200 us; speedup 1.0000x reference)
//
#include <hip/hip_runtime.h>
#include <hip/hip_bf16.h>

#define DD 128

typedef __bf16 bf16x8v __attribute__((ext_vector_type(8)));
typedef float  f32x4   __attribute__((ext_vector_type(4)));

__device__ inline unsigned short f2bf(float f) {
    unsigned u = __builtin_bit_cast(unsigned, f);
    unsigned r = (u + 0x7fffu + ((u >> 16) & 1u)) >> 16;
    return (unsigned short)r;
}
__device__ inline float bflo2f(unsigned p) { return __builtin_bit_cast(float, p << 16); }
__device__ inline float bfhi2f(unsigned p) { return __builtin_bit_cast(float, p & 0xffff0000u); }
__device__ inline float rl_f(int v, int i) {
    return __builtin_bit_cast(float, __builtin_amdgcn_readlane(v, i));
}

// ---- in-degree histogram ----
__global__ __launch_bounds__(256) void k_hist(const int* __restrict__ dst,
                                              int* __restrict__ cnt, int E, int N) {
    int e = blockIdx.x * 256 + threadIdx.x;
    if (e < E) {
        int d = dst[e];
        if ((unsigned)d < (unsigned)N) atomicAdd(&cnt[d], 1);
    }
}

// ---- cast x f32 -> bf16-packed u32 pairs ----
__global__ __launch_bounds__(256) void k_cast(const float4* __restrict__ x4,
                                              uint2* __restrict__ xb, int total4) {
    int gid = blockIdx.x * 256 + threadIdx.x;
    if (gid >= total4) return;
    float4 a = x4[gid];
    uint2 o;
    o.x = (unsigned)f2bf(a.x) | ((unsigned)f2bf(a.y) << 16);
    o.y = (unsigned)f2bf(a.z) | ((unsigned)f2bf(a.w) << 16);
    xb[gid] = o;
}

// ---- exclusive scan of cnt[N] -> rowptr[N+1] ----
__global__ __launch_bounds__(256) void k_scan_block(const int* __restrict__ cnt,
                                                    int* __restrict__ rowptr,
                                                    int* __restrict__ bsums, int N) {
    __shared__ int sh[256];
    int t = threadIdx.x;
    int gid = blockIdx.x * 256 + t;
    int v = (gid < N) ? cnt[gid] : 0;
    sh[t] = v;
    __syncthreads();
    #pragma unroll
    for (int off = 1; off < 256; off <<= 1) {
        int add = (t >= off) ? sh[t - off] : 0;
        __syncthreads();
        sh[t] += add;
        __syncthreads();
    }
    if (gid < N) rowptr[gid] = sh[t] - v;
    if (t == 255) bsums[blockIdx.x] = sh[255];
}

// ---- parallel single-block scan of block sums (nb <= 512) ----
__global__ __launch_bounds__(256) void k_scan_bsums(int* __restrict__ bsums, int nb) {
    __shared__ int sh[512];
    int t = threadIdx.x;
    sh[t]       = (t < nb)       ? bsums[t]       : 0;
    sh[t + 256] = (t + 256 < nb) ? bsums[t + 256] : 0;
    __syncthreads();
    #pragma unroll
    for (int off = 1; off < 512; off <<= 1) {
        int a = (t >= off)       ? sh[t - off]       : 0;
        int b = (t + 256 >= off) ? sh[t + 256 - off] : 0;
        __syncthreads();
        sh[t] += a;
        sh[t + 256] += b;
        __syncthreads();
    }
    if (t < nb)       bsums[t]       = (t == 0) ? 0 : sh[t - 1];
    if (t + 256 < nb) bsums[t + 256] = sh[t + 255];
}

// ---- scan finalize + dinv, and reset cnt for k_fill ----
__global__ __launch_bounds__(256) void k_scan_add(int* __restrict__ rowptr,
                                                  const int* __restrict__ bsums,
                                                  int* __restrict__ cnt,
                                                  float* __restrict__ dinv, int N) {
    int gid = blockIdx.x * 256 + threadIdx.x;
    if (gid < N) {
        int c = cnt[gid];
        int v = rowptr[gid] + bsums[gid >> 8];
        rowptr[gid] = v;
        if (gid == N - 1) rowptr[N] = v + c;
        dinv[gid] = rsqrtf(1.0f + (float)c);
        cnt[gid] = 0;                       // ready for k_fill
    }
}

// ---- fill CSR: ev[pos] = (src, bits(norm)) grouped by dst ----
__global__ __launch_bounds__(256) void k_fill(const int* __restrict__ src, const int* __restrict__ dst,
                                              const int* __restrict__ rowptr, int* __restrict__ fill,
                                              const float* __restrict__ dinv,
                                              int2* __restrict__ ev, int E, int N) {
    int e = blockIdx.x * 256 + threadIdx.x;
    if (e >= E) return;
    int s = src[e], d = dst[e];
    if ((unsigned)s >= (unsigned)N || (unsigned)d >= (unsigned)N) return;
    int pos = rowptr[d] + atomicAdd(&fill[d], 1);
    float nm = dinv[s] * dinv[d];
    ev[pos] = make_int2(s, __builtin_bit_cast(int, nm));
}

// ---- fuse 1: Wf = Wv@Wo (f32), bfo = bv@Wo + bo ----
__global__ __launch_bounds__(256) void k_fuse1(const float* __restrict__ Wv, const float* __restrict__ Wo,
                                               const float* __restrict__ bv, const float* __restrict__ bo,
                                               float* __restrict__ Wf, float* __restrict__ bfo) {
    int gid = blockIdx.x * 256 + threadIdx.x;
    if (gid >= (DD + 1) * DD) return;
    int i = gid >> 7, j = gid & (DD - 1);
    if (i < DD) {
        float acc = 0.f;
        for (int k = 0; k < DD; ++k) acc = fmaf(Wv[i * DD + k], Wo[k * DD + j], acc);
        Wf[i * DD + j] = acc;
    } else {
        float acc = bo[j];
        for (int k = 0; k < DD; ++k) acc = fmaf(bv[k], Wo[k * DD + j], acc);
        bfo[j] = acc;
    }
}

// ---- fuse 2: W2f^T = (W2@Wf)^T bf16, bf2 = b2@Wf + bfo ----
__global__ __launch_bounds__(256) void k_fuse2(const float* __restrict__ W2, const float* __restrict__ Wf,
                                               const float* __restrict__ b2, const float* __restrict__ bfo,
                                               unsigned short* __restrict__ W2ft, float* __restrict__ bf2) {
    int gid = blockIdx.x * 256 + threadIdx.x;
    if (gid >= (DD + 1) * DD) return;
    int i = gid >> 7, j = gid & (DD - 1);
    if (i < DD) {
        float acc = 0.f;
        for (int k = 0; k < DD; ++k) acc = fmaf(W2[i * DD + k], Wf[k * DD + j], acc);
        W2ft[j * DD + i] = f2bf(acc);       // transposed bf16
    } else {
        float acc = bfo[j];
        for (int k = 0; k < DD; ++k) acc = fmaf(b2[k], Wf[k * DD + j], acc);
        bf2[j] = acc;
    }
}

// ---- transpose + cast W[k][n] f32 -> Wt[n][k] bf16 ----
__global__ __launch_bounds__(256) void k_prep(const float* __restrict__ W, unsigned short* __restrict__ Wt) {
    int gid = blockIdx.x * 256 + threadIdx.x;   // 16384
    int k = gid >> 7, n = gid & 127;
    Wt[n * DD + k] = f2bf(W[k * DD + n]);
}

// ---- fused gather + MFMA GEMM ----
// out[n] = (sum_e norm*h[src] + dinv[n]^2*h[n]) @ Wt^T + bias  (+relu)
// 8 waves/block, 128 rows/block, wave-private 16-row LDS tile (XOR-swizzled),
// Wt staged in LDS (swizzled). One barrier total. 64KB LDS -> 2 blocks/CU.
// MFMA layouts (m89/m91): a/b frag: idx=l&15, k=(l>>4)*8+j; D: col=l&15, row=(l>>4)*4+reg.
template<int OUTF32, int RELU>
__global__ __launch_bounds__(512, 4) void k_fgg(const int* __restrict__ rowptr, const int2* __restrict__ ev,
                                                const unsigned* __restrict__ h32, const float* __restrict__ dinv,
                                                const unsigned* __restrict__ Wt32, const float* __restrict__ bias,
                                                void* __restrict__ outp, int N) {
    __shared__ unsigned lds[16384];   // [0,8192): Wt swizzled; [8192,16384): 8 x 16x64 A tiles
    int t = threadIdx.x;
    #pragma unroll
    for (int p = 0; p < 16; ++p) {
        int i = p * 512 + t;
        lds[(i & ~63) | ((i & 63) ^ (((i >> 6) & 7) << 2))] = Wt32[i];
    }
    __syncthreads();

    int w = t >> 6, l = t & 63;
    int lo = l & 15, hi = l >> 4;
    int m0 = blockIdx.x * 128 + w * 16;
    unsigned* A = &lds[8192 + w * 1024];

    // preload row ptrs (lanes 0..16) and dinv (lanes 0..15) for this wave's 16 rows
    int rpidx = m0 + l; if (rpidx > N) rpidx = N;
    int rp = (l < 17) ? rowptr[rpidx] : 0;
    int dvidx = m0 + l; if (dvidx > N - 1) dvidx = N - 1;
    float dv = (l < 16) ? dinv[dvidx] : 0.f;

    // prefetch edge chunk for row 0
    int beg0 = __builtin_amdgcn_readlane(rp, 0);
    int end0 = __builtin_amdgcn_readlane(rp, 1);
    int cpre = end0 - beg0; if (cpre > 64) cpre = 64;
    int2 me = (cpre > 0) ? ev[beg0 + (l < cpre ? l : cpre - 1)] : make_int2(0, 0);

    for (int r = 0; r < 16; ++r) {
        int n = m0 + r;
        int b_ = __builtin_amdgcn_readlane(rp, r);
        int e_ = __builtin_amdgcn_readlane(rp, r + 1);
        int deg = e_ - b_;
        int2 mc = me;
        if (r < 15) {   // prefetch next row's chunk before consuming this one
            int b1 = __builtin_amdgcn_readlane(rp, r + 1);
            int e1 = __builtin_amdgcn_readlane(rp, r + 2);
            int c1 = e1 - b1; if (c1 > 64) c1 = 64;
            me = (c1 > 0) ? ev[b1 + (l < c1 ? l : c1 - 1)] : make_int2(0, 0);
        }
        float ax = 0.f, ay = 0.f;
        if (n < N) {
            int c = deg < 64 ? deg : 64;
            int i = 0;
            for (; i + 8 <= c; i += 8) {
                unsigned p[8]; float wv[8];
                #pragma unroll
                for (int q = 0; q < 8; ++q) {
                    int s = __builtin_amdgcn_readlane(mc.x, i + q);
                    p[q] = h32[(size_t)s * 64 + l];
                }
                #pragma unroll
                for (int q = 0; q < 8; ++q) wv[q] = rl_f(mc.y, i + q);
                #pragma unroll
                for (int q = 0; q < 8; ++q) {
                    ax = fmaf(wv[q], bflo2f(p[q]), ax);
                    ay = fmaf(wv[q], bfhi2f(p[q]), ay);
                }
            }
            for (; i < c; ++i) {
                int s = __builtin_amdgcn_readlane(mc.x, i);
                unsigned pq = h32[(size_t)s * 64 + l];
                float wq = rl_f(mc.y, i);
                ax = fmaf(wq, bflo2f(pq), ax);
                ay = fmaf(wq, bfhi2f(pq), ay);
            }
            for (int base = 64; base < deg; base += 64) {   // rare high-degree tail
                int cc = deg - base; if (cc > 64) cc = 64;
                int2 m2 = ev[b_ + base + (l < cc ? l : cc - 1)];
                for (int ii = 0; ii < cc; ++ii) {
                    int s = __builtin_amdgcn_readlane(m2.x, ii);
                    unsigned pq = h32[(size_t)s * 64 + l];
                    float wq = rl_f(m2.y, ii);
                    ax = fmaf(wq, bflo2f(pq), ax);
                    ay = fmaf(wq, bfhi2f(pq), ay);
                }
            }
            unsigned ps = h32[(size_t)n * 64 + l];
            float di = __builtin_bit_cast(float, __builtin_amdgcn_readlane(__builtin_bit_cast(int, dv), r));
            float di2 = di * di;
            ax = fmaf(di2, bflo2f(ps), ax);
            ay = fmaf(di2, bfhi2f(ps), ay);
        }
        unsigned po = (unsigned)f2bf(ax) | ((unsigned)f2bf(ay) << 16);
        A[r * 64 + (l ^ ((r & 7) << 2))] = po;   // swizzled write, conflict-free
    }

    // MFMA over this wave's 16-row tile (same-wave LDS, no barrier needed)
    f32x4 acc[8] = {};
    #pragma unroll
    for (int kk = 0; kk < 4; ++kk) {
        int co = (kk * 16 + hi * 4) ^ ((lo & 7) << 2);
        bf16x8v af = *reinterpret_cast<bf16x8v*>(&A[lo * 64 + co]);
        #pragma unroll
        for (int nt = 0; nt < 8; ++nt) {
            bf16x8v bfrag = *reinterpret_cast<bf16x8v*>(&lds[(nt * 16 + lo) * 64 + co]);
            acc[nt] = __builtin_amdgcn_mfma_f32_16x16x32_bf16(af, bfrag, acc[nt], 0, 0, 0);
        }
    }

    #pragma unroll
    for (int nt = 0; nt < 8; ++nt) {
        float bv_ = bias[nt * 16 + lo];
        #pragma unroll
        for (int r4 = 0; r4 < 4; ++r4) {
            int rr = m0 + hi * 4 + r4;
            if (rr < N) {
                float v = acc[nt][r4] + bv_;
                if (RELU) v = fmaxf(v, 0.f);
                if (OUTF32) ((float*)outp)[(size_t)rr * DD + nt * 16 + lo] = v;
                else ((unsigned short*)outp)[(size_t)rr * DD + nt * 16 + lo] = f2bf(v);
            }
        }
    }
}

extern "C" void kernel_launch(void* const* d_in, const int* in_sizes, int n_in,
                              void* d_out, int out_size, void* d_ws, size_t ws_size,
                              hipStream_t stream) {
    const float* x  = (const float*)d_in[0];
    const int*   ei = (const int*)d_in[1];
    const float* W1 = (const float*)d_in[2];
    const float* b1 = (const float*)d_in[3];
    const float* W2 = (const float*)d_in[4];
    const float* b2 = (const float*)d_in[5];
    // Wq/bq/Wk/bk (6..9) dead: softmax over seq_len=1 is identity.
    const float* Wv = (const float*)d_in[10];
    const float* bv = (const float*)d_in[11];
    const float* Wo = (const float*)d_in[12];
    const float* bo = (const float*)d_in[13];
    int N = in_sizes[0] / DD;
    int E = in_sizes[1] / 2;
    const int* src = ei;
    const int* dst = ei + E;
    float* out = (float*)d_out;

    unsigned* xb  = (unsigned*)d_ws;                  // N*64 u32 (bf16 x)
    unsigned* h1  = xb + (size_t)N * 64;              // N*64 u32 (bf16 h1)
    float* dinv   = (float*)(h1 + (size_t)N * 64);    // N
    float* Wf     = dinv + N;                         // 128*128 f32
    float* bfo    = Wf + DD * DD;                     // 128
    float* bf2    = bfo + DD;                         // 128
    unsigned short* Wt1  = (unsigned short*)(bf2 + DD);   // 128*128 bf16
    unsigned short* W2ft = Wt1 + DD * DD;                 // 128*128 bf16
    int* cnt    = (int*)(W2ft + DD * DD);             // N
    int* rowptr = cnt + N;                            // N+1
    int* bsums  = rowptr + N + 1;                     // 512
    int2* ev    = (int2*)(((uintptr_t)(bsums + 512) + 15) & ~(uintptr_t)15);  // E

    int nb = (N + 255) / 256;

    // CSR build (shared by both layers)
    hipMemsetAsync(cnt, 0, (size_t)N * sizeof(int), stream);
    k_cast<<<(N * 32 + 255) / 256, 256, 0, stream>>>((const float4*)x, (uint2*)xb, N * 32);
    k_hist<<<(E + 255) / 256, 256, 0, stream>>>(dst, cnt, E, N);
    k_scan_block<<<nb, 256, 0, stream>>>(cnt, rowptr, bsums, N);
    k_scan_bsums<<<1, 256, 0, stream>>>(bsums, nb);
    k_scan_add<<<nb, 256, 0, stream>>>(rowptr, bsums, cnt, dinv, N);
    k_fill<<<(E + 255) / 256, 256, 0, stream>>>(src, dst, rowptr, cnt, dinv, ev, E, N);

    // weight prep: Wf = Wv@Wo, then W2f = W2@Wf (MHA folded into layer-2 GEMM)
    k_fuse1<<<((DD + 1) * DD + 255) / 256, 256, 0, stream>>>(Wv, Wo, bv, bo, Wf, bfo);
    k_fuse2<<<((DD + 1) * DD + 255) / 256, 256, 0, stream>>>(W2, Wf, b2, bfo, W2ft, bf2);
    k_prep<<<64, 256, 0, stream>>>(W1, Wt1);

    int fgg_blocks = (N + 127) / 128;

    // layer 1: h1 = relu(G(xb) @ W1 + b1)
    k_fgg<0, 1><<<fgg_blocks, 512, 0, stream>>>(rowptr, ev, xb, dinv,
                                                (const unsigned*)Wt1, b1, h1, N);
    // layer 2 + MHA: out = G(h1) @ W2f + bf2
    k_fgg<1, 0><<<fgg_blocks, 512, 0, stream>>>(rowptr, ev, h1, dinv,
                                                (const unsigned*)W2ft, bf2, out, N);
}

// Round 8
// 203.318 us; speedup vs baseline: 1.3142x; 1.3142x over previous
//
#include <hip/hip_runtime.h>
#include <hip/hip_bf16.h>

#define DD 128

typedef __bf16 bf16x8v __attribute__((ext_vector_type(8)));
typedef float  f32x4   __attribute__((ext_vector_type(4)));

__device__ inline unsigned short f2bf(float f) {
    unsigned u = __builtin_bit_cast(unsigned, f);
    unsigned r = (u + 0x7fffu + ((u >> 16) & 1u)) >> 16;
    return (unsigned short)r;
}
__device__ inline float bflo2f(unsigned p) { return __builtin_bit_cast(float, p << 16); }
__device__ inline float bfhi2f(unsigned p) { return __builtin_bit_cast(float, p & 0xffff0000u); }
__device__ inline float rl_f(int v, int i) {
    return __builtin_bit_cast(float, __builtin_amdgcn_readlane(v, i));
}

// ---- in-degree histogram ----
__global__ __launch_bounds__(256) void k_hist(const int* __restrict__ dst,
                                              int* __restrict__ cnt, int E, int N) {
    int e = blockIdx.x * 256 + threadIdx.x;
    if (e < E) {
        int d = dst[e];
        if ((unsigned)d < (unsigned)N) atomicAdd(&cnt[d], 1);
    }
}

// ---- exclusive scan of cnt[N] -> rowptr[N+1] ----
__global__ __launch_bounds__(256) void k_scan_block(const int* __restrict__ cnt,
                                                    int* __restrict__ rowptr,
                                                    int* __restrict__ bsums, int N) {
    __shared__ int sh[256];
    int t = threadIdx.x;
    int gid = blockIdx.x * 256 + t;
    int v = (gid < N) ? cnt[gid] : 0;
    sh[t] = v;
    __syncthreads();
    #pragma unroll
    for (int off = 1; off < 256; off <<= 1) {
        int add = (t >= off) ? sh[t - off] : 0;
        __syncthreads();
        sh[t] += add;
        __syncthreads();
    }
    if (gid < N) rowptr[gid] = sh[t] - v;
    if (t == 255) bsums[blockIdx.x] = sh[255];
}

// ---- parallel single-block scan of block sums (nb <= 512) ----
__global__ __launch_bounds__(256) void k_scan_bsums(int* __restrict__ bsums, int nb) {
    __shared__ int sh[512];
    int t = threadIdx.x;
    sh[t]       = (t < nb)       ? bsums[t]       : 0;
    sh[t + 256] = (t + 256 < nb) ? bsums[t + 256] : 0;
    __syncthreads();
    #pragma unroll
    for (int off = 1; off < 512; off <<= 1) {
        int a = (t >= off)       ? sh[t - off]       : 0;
        int b = (t + 256 >= off) ? sh[t + 256 - off] : 0;
        __syncthreads();
        sh[t] += a;
        sh[t + 256] += b;
        __syncthreads();
    }
    if (t < nb)       bsums[t]       = (t == 0) ? 0 : sh[t - 1];
    if (t + 256 < nb) bsums[t + 256] = sh[t + 255];
}

// ---- scan finalize + dinv, and reset cnt for k_fill ----
__global__ __launch_bounds__(256) void k_scan_add(int* __restrict__ rowptr,
                                                  const int* __restrict__ bsums,
                                                  int* __restrict__ cnt,
                                                  float* __restrict__ dinv, int N) {
    int gid = blockIdx.x * 256 + threadIdx.x;
    if (gid < N) {
        int c = cnt[gid];
        int v = rowptr[gid] + bsums[gid >> 8];
        rowptr[gid] = v;
        if (gid == N - 1) rowptr[N] = v + c;
        dinv[gid] = rsqrtf(1.0f + (float)c);
        cnt[gid] = 0;                       // ready for k_fill
    }
}

// ---- fill CSR: ev[pos] = (src, bits(norm)) grouped by dst ----
__global__ __launch_bounds__(256) void k_fill(const int* __restrict__ src, const int* __restrict__ dst,
                                              const int* __restrict__ rowptr, int* __restrict__ fill,
                                              const float* __restrict__ dinv,
                                              int2* __restrict__ ev, int E, int N) {
    int e = blockIdx.x * 256 + threadIdx.x;
    if (e >= E) return;
    int s = src[e], d = dst[e];
    if ((unsigned)s >= (unsigned)N || (unsigned)d >= (unsigned)N) return;
    int pos = rowptr[d] + atomicAdd(&fill[d], 1);
    float nm = dinv[s] * dinv[d];
    ev[pos] = make_int2(s, __builtin_bit_cast(int, nm));
}

// ---- fuse 1: Wf = Wv@Wo (f32), bfo = bv@Wo + bo ----
__global__ __launch_bounds__(256) void k_fuse1(const float* __restrict__ Wv, const float* __restrict__ Wo,
                                               const float* __restrict__ bv, const float* __restrict__ bo,
                                               float* __restrict__ Wf, float* __restrict__ bfo) {
    int gid = blockIdx.x * 256 + threadIdx.x;
    if (gid >= (DD + 1) * DD) return;
    int i = gid >> 7, j = gid & (DD - 1);
    if (i < DD) {
        float acc = 0.f;
        for (int k = 0; k < DD; ++k) acc = fmaf(Wv[i * DD + k], Wo[k * DD + j], acc);
        Wf[i * DD + j] = acc;
    } else {
        float acc = bo[j];
        for (int k = 0; k < DD; ++k) acc = fmaf(bv[k], Wo[k * DD + j], acc);
        bfo[j] = acc;
    }
}

// ---- fuse 2: W2f^T = (W2@Wf)^T bf16, bf2 = b2@Wf + bfo ----
__global__ __launch_bounds__(256) void k_fuse2(const float* __restrict__ W2, const float* __restrict__ Wf,
                                               const float* __restrict__ b2, const float* __restrict__ bfo,
                                               unsigned short* __restrict__ W2ft, float* __restrict__ bf2) {
    int gid = blockIdx.x * 256 + threadIdx.x;
    if (gid >= (DD + 1) * DD) return;
    int i = gid >> 7, j = gid & (DD - 1);
    if (i < DD) {
        float acc = 0.f;
        for (int k = 0; k < DD; ++k) acc = fmaf(W2[i * DD + k], Wf[k * DD + j], acc);
        W2ft[j * DD + i] = f2bf(acc);       // transposed bf16
    } else {
        float acc = bfo[j];
        for (int k = 0; k < DD; ++k) acc = fmaf(b2[k], Wf[k * DD + j], acc);
        bf2[j] = acc;
    }
}

// ---- transpose + cast W[k][n] f32 -> Wt[n][k] bf16 ----
__global__ __launch_bounds__(256) void k_prep(const float* __restrict__ W, unsigned short* __restrict__ Wt) {
    int gid = blockIdx.x * 256 + threadIdx.x;   // 16384
    int k = gid >> 7, n = gid & 127;
    Wt[n * DD + k] = f2bf(W[k * DD + n]);
}

// ---- MFMA GEMM: C[M x 128] = A[M x 128] @ Wt^T (+bias) ----
// Persistent blocks, 64 rows/tile, 4 waves x 16 rows. B fragments preloaded in
// registers; no LDS, no syncthreads.
// Layouts (m89/m91): a/b frag: idx=l&15, k=(l>>4)*8+j; D: col=l&15, row=(l>>4)*4+reg.
template<int AF32, int OUTF32>
__global__ __launch_bounds__(256, 2) void k_gemm_mfma(const void* __restrict__ Av,
                                                      const unsigned short* __restrict__ Wt,
                                                      const float* __restrict__ bias,
                                                      void* __restrict__ Cv, int M) {
    int w  = threadIdx.x >> 6;
    int l  = threadIdx.x & 63;
    int lr = l & 15, lg = l >> 4;

    bf16x8v bfr[8][4];
    #pragma unroll
    for (int nt = 0; nt < 8; ++nt)
        #pragma unroll
        for (int kk = 0; kk < 4; ++kk)
            bfr[nt][kk] = *reinterpret_cast<const bf16x8v*>(Wt + (nt * 16 + lr) * DD + kk * 32 + lg * 8);

    float bvals[8];
    #pragma unroll
    for (int nt = 0; nt < 8; ++nt) bvals[nt] = bias ? bias[nt * 16 + lr] : 0.f;

    int tiles = (M + 63) >> 6;
    for (int t = blockIdx.x; t < tiles; t += gridDim.x) {
        int m0 = t * 64 + w * 16;
        int row = m0 + lr;
        int rowc = row < M ? row : (M - 1);

        bf16x8v af[4];
        if (AF32) {
            const float* Af = (const float*)Av;
            #pragma unroll
            for (int kk = 0; kk < 4; ++kk) {
                const float* p = Af + (size_t)rowc * DD + kk * 32 + lg * 8;
                float4 u0 = *reinterpret_cast<const float4*>(p);
                float4 u1 = *reinterpret_cast<const float4*>(p + 4);
                af[kk][0] = (__bf16)u0.x; af[kk][1] = (__bf16)u0.y;
                af[kk][2] = (__bf16)u0.z; af[kk][3] = (__bf16)u0.w;
                af[kk][4] = (__bf16)u1.x; af[kk][5] = (__bf16)u1.y;
                af[kk][6] = (__bf16)u1.z; af[kk][7] = (__bf16)u1.w;
            }
        } else {
            const unsigned short* Ab = (const unsigned short*)Av;
            #pragma unroll
            for (int kk = 0; kk < 4; ++kk)
                af[kk] = *reinterpret_cast<const bf16x8v*>(Ab + (size_t)rowc * DD + kk * 32 + lg * 8);
        }

        f32x4 acc[8] = {};
        #pragma unroll
        for (int kk = 0; kk < 4; ++kk)
            #pragma unroll
            for (int nt = 0; nt < 8; ++nt)
                acc[nt] = __builtin_amdgcn_mfma_f32_16x16x32_bf16(af[kk], bfr[nt][kk], acc[nt], 0, 0, 0);

        #pragma unroll
        for (int nt = 0; nt < 8; ++nt) {
            #pragma unroll
            for (int r = 0; r < 4; ++r) {
                int rr = m0 + lg * 4 + r;
                if (rr < M) {
                    float v = acc[nt][r] + bvals[nt];
                    if (OUTF32) ((float*)Cv)[(size_t)rr * DD + nt * 16 + lr] = v;
                    else ((unsigned short*)Cv)[(size_t)rr * DD + nt * 16 + lr] = f2bf(v);
                }
            }
        }
    }
}

// ---- CSR gather v3: 16 rows/wave, rowptr preload, chunk prefetch,
//      predicated 8-wide row loads (one vmcnt round per typical row) ----
template<int OUTF32, int RELU>
__global__ __launch_bounds__(256) void k_gather16(const int* __restrict__ rowptr, const int2* __restrict__ ev,
                                                  const unsigned* __restrict__ h32, const float* __restrict__ dinv,
                                                  const float* __restrict__ bias, void* __restrict__ outp, int N) {
    int l = threadIdx.x & 63;
    int g = blockIdx.x * 4 + (threadIdx.x >> 6);   // 16-row group id
    int m0 = g * 16;
    if (m0 >= N) return;
    float2 bb = reinterpret_cast<const float2*>(bias)[l];

    // preload 17 row ptrs (lanes 0..16) and 16 dinv (lanes 0..15)
    int rpidx = m0 + l; if (rpidx > N) rpidx = N;
    int rp = (l < 17) ? rowptr[rpidx] : 0;
    int dvidx = m0 + l; if (dvidx >= N) dvidx = N - 1;
    float dv = (l < 16) ? dinv[dvidx] : 0.f;

    // prefetch edge chunk for row 0
    int b0 = __builtin_amdgcn_readlane(rp, 0);
    int e0 = __builtin_amdgcn_readlane(rp, 1);
    int c0 = e0 - b0; if (c0 > 64) c0 = 64;
    int2 me = (c0 > 0) ? ev[b0 + (l < c0 ? l : c0 - 1)] : make_int2(0, 0);

    for (int r = 0; r < 16; ++r) {
        int n = m0 + r;
        if (n >= N) break;
        int b_ = __builtin_amdgcn_readlane(rp, r);
        int e_ = __builtin_amdgcn_readlane(rp, r + 1);
        int deg = e_ - b_;
        int2 mc = me;
        if (r < 15) {   // prefetch next row's chunk before consuming this one
            int b1 = __builtin_amdgcn_readlane(rp, r + 1);
            int e1 = __builtin_amdgcn_readlane(rp, r + 2);
            int c1 = e1 - b1; if (c1 > 64) c1 = 64;
            me = (c1 > 0) ? ev[b1 + (l < c1 ? l : c1 - 1)] : make_int2(0, 0);
        }

        float ax = 0.f, ay = 0.f;
        int c = deg < 64 ? deg : 64;
        for (int i = 0; i < c; i += 8) {
            unsigned p[8]; float wv[8];
            #pragma unroll
            for (int q = 0; q < 8; ++q) {
                int idx = (i + q < c) ? i + q : c - 1;          // clamp (uniform)
                int s = __builtin_amdgcn_readlane(mc.x, idx);
                p[q] = h32[(size_t)s * 64 + l];                 // 8 independent loads
                wv[q] = (i + q < c) ? rl_f(mc.y, idx) : 0.f;    // predicated weight
            }
            #pragma unroll
            for (int q = 0; q < 8; ++q) {
                ax = fmaf(wv[q], bflo2f(p[q]), ax);
                ay = fmaf(wv[q], bfhi2f(p[q]), ay);
            }
        }
        for (int base = 64; base < deg; base += 64) {   // rare high-degree tail
            int cc = deg - base; if (cc > 64) cc = 64;
            int2 m2 = ev[b_ + base + (l < cc ? l : cc - 1)];
            for (int ii = 0; ii < cc; ++ii) {
                int s = __builtin_amdgcn_readlane(m2.x, ii);
                unsigned pq = h32[(size_t)s * 64 + l];
                float wq = rl_f(m2.y, ii);
                ax = fmaf(wq, bflo2f(pq), ax);
                ay = fmaf(wq, bfhi2f(pq), ay);
            }
        }

        unsigned ps = h32[(size_t)n * 64 + l];
        float di = __builtin_bit_cast(float, __builtin_amdgcn_readlane(__builtin_bit_cast(int, dv), r));
        float di2 = di * di;
        float ox = fmaf(di2, bflo2f(ps), ax) + bb.x;
        float oy = fmaf(di2, bfhi2f(ps), ay) + bb.y;
        if (RELU) { ox = fmaxf(ox, 0.f); oy = fmaxf(oy, 0.f); }
        if (OUTF32) {
            reinterpret_cast<float2*>(outp)[(size_t)n * 64 + l] = make_float2(ox, oy);
        } else {
            unsigned po = (unsigned)f2bf(ox) | ((unsigned)f2bf(oy) << 16);
            reinterpret_cast<unsigned*>(outp)[(size_t)n * 64 + l] = po;
        }
    }
}

extern "C" void kernel_launch(void* const* d_in, const int* in_sizes, int n_in,
                              void* d_out, int out_size, void* d_ws, size_t ws_size,
                              hipStream_t stream) {
    const float* x  = (const float*)d_in[0];
    const int*   ei = (const int*)d_in[1];
    const float* W1 = (const float*)d_in[2];
    const float* b1 = (const float*)d_in[3];
    const float* W2 = (const float*)d_in[4];
    const float* b2 = (const float*)d_in[5];
    // Wq/bq/Wk/bk (6..9) dead: softmax over seq_len=1 is identity.
    const float* Wv = (const float*)d_in[10];
    const float* bv = (const float*)d_in[11];
    const float* Wo = (const float*)d_in[12];
    const float* bo = (const float*)d_in[13];
    int N = in_sizes[0] / DD;
    int E = in_sizes[1] / 2;
    const int* src = ei;
    const int* dst = ei + E;
    float* out = (float*)d_out;

    unsigned* hA  = (unsigned*)d_ws;                  // N*64 u32 (bf16 GEMM out)
    unsigned* h1  = hA + (size_t)N * 64;              // N*64 u32 (bf16 h1)
    float* dinv   = (float*)(h1 + (size_t)N * 64);    // N
    float* Wf     = dinv + N;                         // 128*128 f32
    float* bfo    = Wf + DD * DD;                     // 128
    float* bf2    = bfo + DD;                         // 128
    unsigned short* Wt1  = (unsigned short*)(bf2 + DD);   // 128*128 bf16
    unsigned short* W2ft = Wt1 + DD * DD;                 // 128*128 bf16
    int* cnt    = (int*)(W2ft + DD * DD);             // N
    int* rowptr = cnt + N;                            // N+1
    int* bsums  = rowptr + N + 1;                     // 512
    int2* ev    = (int2*)(((uintptr_t)(bsums + 512) + 15) & ~(uintptr_t)15);  // E

    int nb = (N + 255) / 256;

    // CSR build (shared by both layers)
    hipMemsetAsync(cnt, 0, (size_t)N * sizeof(int), stream);
    k_hist<<<(E + 255) / 256, 256, 0, stream>>>(dst, cnt, E, N);
    k_scan_block<<<nb, 256, 0, stream>>>(cnt, rowptr, bsums, N);
    k_scan_bsums<<<1, 256, 0, stream>>>(bsums, nb);
    k_scan_add<<<nb, 256, 0, stream>>>(rowptr, bsums, cnt, dinv, N);
    k_fill<<<(E + 255) / 256, 256, 0, stream>>>(src, dst, rowptr, cnt, dinv, ev, E, N);

    // weight prep: Wf = Wv@Wo, W2f = W2@Wf (MHA folded into layer-2 GEMM)
    k_fuse1<<<((DD + 1) * DD + 255) / 256, 256, 0, stream>>>(Wv, Wo, bv, bo, Wf, bfo);
    k_fuse2<<<((DD + 1) * DD + 255) / 256, 256, 0, stream>>>(W2, Wf, b2, bfo, W2ft, bf2);
    k_prep<<<64, 256, 0, stream>>>(W1, Wt1);

    int gat_blocks = (N + 63) / 64;   // 4 waves/block, 16 rows/wave

    // layer 1: hA = x@W1 ; h1 = relu(G(hA) + b1)
    k_gemm_mfma<1, 0><<<512, 256, 0, stream>>>(x, Wt1, nullptr, hA, N);
    k_gather16<0, 1><<<gat_blocks, 256, 0, stream>>>(rowptr, ev, hA, dinv, b1, h1, N);

    // layer 2 + MHA: hA = h1@(W2·Wv·Wo) ; out = G(hA) + bf2
    k_gemm_mfma<0, 0><<<512, 256, 0, stream>>>(h1, W2ft, nullptr, hA, N);
    k_gather16<1, 0><<<gat_blocks, 256, 0, stream>>>(rowptr, ev, hA, dinv, bf2, out, N);
}

// Round 9
// 191.880 us; speedup vs baseline: 1.3925x; 1.0596x over previous
//
#include <hip/hip_runtime.h>
#include <hip/hip_bf16.h>

#define DD 128

typedef __bf16 bf16x8v __attribute__((ext_vector_type(8)));
typedef float  f32x4   __attribute__((ext_vector_type(4)));

__device__ inline unsigned short f2bf(float f) {
    unsigned u = __builtin_bit_cast(unsigned, f);
    unsigned r = (u + 0x7fffu + ((u >> 16) & 1u)) >> 16;
    return (unsigned short)r;
}
__device__ inline float bflo2f(unsigned p) { return __builtin_bit_cast(float, p << 16); }
__device__ inline float bfhi2f(unsigned p) { return __builtin_bit_cast(float, p & 0xffff0000u); }
__device__ inline float rl_f(int v, int i) {
    return __builtin_bit_cast(float, __builtin_amdgcn_readlane(v, i));
}

// ---- in-degree histogram ----
__global__ __launch_bounds__(256) void k_hist(const int* __restrict__ dst,
                                              int* __restrict__ cnt, int E, int N) {
    int e = blockIdx.x * 256 + threadIdx.x;
    if (e < E) {
        int d = dst[e];
        if ((unsigned)d < (unsigned)N) atomicAdd(&cnt[d], 1);
    }
}

// ---- exclusive scan of cnt[N] -> rowptr[N+1] ----
__global__ __launch_bounds__(256) void k_scan_block(const int* __restrict__ cnt,
                                                    int* __restrict__ rowptr,
                                                    int* __restrict__ bsums, int N) {
    __shared__ int sh[256];
    int t = threadIdx.x;
    int gid = blockIdx.x * 256 + t;
    int v = (gid < N) ? cnt[gid] : 0;
    sh[t] = v;
    __syncthreads();
    #pragma unroll
    for (int off = 1; off < 256; off <<= 1) {
        int add = (t >= off) ? sh[t - off] : 0;
        __syncthreads();
        sh[t] += add;
        __syncthreads();
    }
    if (gid < N) rowptr[gid] = sh[t] - v;
    if (t == 255) bsums[blockIdx.x] = sh[255];
}

// ---- parallel single-block scan of block sums (nb <= 512) ----
__global__ __launch_bounds__(256) void k_scan_bsums(int* __restrict__ bsums, int nb) {
    __shared__ int sh[512];
    int t = threadIdx.x;
    sh[t]       = (t < nb)       ? bsums[t]       : 0;
    sh[t + 256] = (t + 256 < nb) ? bsums[t + 256] : 0;
    __syncthreads();
    #pragma unroll
    for (int off = 1; off < 512; off <<= 1) {
        int a = (t >= off)       ? sh[t - off]       : 0;
        int b = (t + 256 >= off) ? sh[t + 256 - off] : 0;
        __syncthreads();
        sh[t] += a;
        sh[t + 256] += b;
        __syncthreads();
    }
    if (t < nb)       bsums[t]       = (t == 0) ? 0 : sh[t - 1];
    if (t + 256 < nb) bsums[t + 256] = sh[t + 255];
}

// ---- scan finalize + dinv, and reset cnt for k_fill ----
__global__ __launch_bounds__(256) void k_scan_add(int* __restrict__ rowptr,
                                                  const int* __restrict__ bsums,
                                                  int* __restrict__ cnt,
                                                  float* __restrict__ dinv, int N) {
    int gid = blockIdx.x * 256 + threadIdx.x;
    if (gid < N) {
        int c = cnt[gid];
        int v = rowptr[gid] + bsums[gid >> 8];
        rowptr[gid] = v;
        if (gid == N - 1) rowptr[N] = v + c;
        dinv[gid] = rsqrtf(1.0f + (float)c);
        cnt[gid] = 0;                       // ready for k_fill
    }
}

// ---- fill CSR: ev[pos] = (src, bits(norm)) grouped by dst ----
__global__ __launch_bounds__(256) void k_fill(const int* __restrict__ src, const int* __restrict__ dst,
                                              const int* __restrict__ rowptr, int* __restrict__ fill,
                                              const float* __restrict__ dinv,
                                              int2* __restrict__ ev, int E, int N) {
    int e = blockIdx.x * 256 + threadIdx.x;
    if (e >= E) return;
    int s = src[e], d = dst[e];
    if ((unsigned)s >= (unsigned)N || (unsigned)d >= (unsigned)N) return;
    int pos = rowptr[d] + atomicAdd(&fill[d], 1);
    float nm = dinv[s] * dinv[d];
    ev[pos] = make_int2(s, __builtin_bit_cast(int, nm));
}

// ---- fuse 1: Wf = Wv@Wo (f32), bfo = bv@Wo + bo ----
__global__ __launch_bounds__(256) void k_fuse1(const float* __restrict__ Wv, const float* __restrict__ Wo,
                                               const float* __restrict__ bv, const float* __restrict__ bo,
                                               float* __restrict__ Wf, float* __restrict__ bfo) {
    int gid = blockIdx.x * 256 + threadIdx.x;
    if (gid >= (DD + 1) * DD) return;
    int i = gid >> 7, j = gid & (DD - 1);
    if (i < DD) {
        float acc = 0.f;
        for (int k = 0; k < DD; ++k) acc = fmaf(Wv[i * DD + k], Wo[k * DD + j], acc);
        Wf[i * DD + j] = acc;
    } else {
        float acc = bo[j];
        for (int k = 0; k < DD; ++k) acc = fmaf(bv[k], Wo[k * DD + j], acc);
        bfo[j] = acc;
    }
}

// ---- fuse 2 + W1 prep (merged): blocks 0..64 -> W2f^T bf16 + bf2; blocks 65..128 -> Wt1 ----
__global__ __launch_bounds__(256) void k_wprep(const float* __restrict__ W2, const float* __restrict__ Wf,
                                               const float* __restrict__ b2, const float* __restrict__ bfo,
                                               unsigned short* __restrict__ W2ft, float* __restrict__ bf2,
                                               const float* __restrict__ W1, unsigned short* __restrict__ Wt1) {
    int blk = blockIdx.x;
    if (blk < 65) {
        int gid = blk * 256 + threadIdx.x;
        if (gid >= (DD + 1) * DD) return;
        int i = gid >> 7, j = gid & (DD - 1);
        if (i < DD) {
            float acc = 0.f;
            for (int k = 0; k < DD; ++k) acc = fmaf(W2[i * DD + k], Wf[k * DD + j], acc);
            W2ft[j * DD + i] = f2bf(acc);       // transposed bf16
        } else {
            float acc = bfo[j];
            for (int k = 0; k < DD; ++k) acc = fmaf(b2[k], Wf[k * DD + j], acc);
            bf2[j] = acc;
        }
    } else {
        int gid = (blk - 65) * 256 + threadIdx.x;   // 16384
        int k = gid >> 7, n = gid & 127;
        Wt1[n * DD + k] = f2bf(W1[k * DD + n]);
    }
}

// ---- MFMA GEMM: C[M x 128] = A[M x 128] @ Wt^T (+bias) ----
// Persistent blocks, 64 rows/tile, 4 waves x 16 rows. B fragments preloaded in
// registers; no LDS, no syncthreads.
// Layouts (m89/m91): a/b frag: idx=l&15, k=(l>>4)*8+j; D: col=l&15, row=(l>>4)*4+reg.
template<int AF32, int OUTF32>
__global__ __launch_bounds__(256, 2) void k_gemm_mfma(const void* __restrict__ Av,
                                                      const unsigned short* __restrict__ Wt,
                                                      const float* __restrict__ bias,
                                                      void* __restrict__ Cv, int M) {
    int w  = threadIdx.x >> 6;
    int l  = threadIdx.x & 63;
    int lr = l & 15, lg = l >> 4;

    bf16x8v bfr[8][4];
    #pragma unroll
    for (int nt = 0; nt < 8; ++nt)
        #pragma unroll
        for (int kk = 0; kk < 4; ++kk)
            bfr[nt][kk] = *reinterpret_cast<const bf16x8v*>(Wt + (nt * 16 + lr) * DD + kk * 32 + lg * 8);

    float bvals[8];
    #pragma unroll
    for (int nt = 0; nt < 8; ++nt) bvals[nt] = bias ? bias[nt * 16 + lr] : 0.f;

    int tiles = (M + 63) >> 6;
    for (int t = blockIdx.x; t < tiles; t += gridDim.x) {
        int m0 = t * 64 + w * 16;
        int row = m0 + lr;
        int rowc = row < M ? row : (M - 1);

        bf16x8v af[4];
        if (AF32) {
            const float* Af = (const float*)Av;
            #pragma unroll
            for (int kk = 0; kk < 4; ++kk) {
                const float* p = Af + (size_t)rowc * DD + kk * 32 + lg * 8;
                float4 u0 = *reinterpret_cast<const float4*>(p);
                float4 u1 = *reinterpret_cast<const float4*>(p + 4);
                af[kk][0] = (__bf16)u0.x; af[kk][1] = (__bf16)u0.y;
                af[kk][2] = (__bf16)u0.z; af[kk][3] = (__bf16)u0.w;
                af[kk][4] = (__bf16)u1.x; af[kk][5] = (__bf16)u1.y;
                af[kk][6] = (__bf16)u1.z; af[kk][7] = (__bf16)u1.w;
            }
        } else {
            const unsigned short* Ab = (const unsigned short*)Av;
            #pragma unroll
            for (int kk = 0; kk < 4; ++kk)
                af[kk] = *reinterpret_cast<const bf16x8v*>(Ab + (size_t)rowc * DD + kk * 32 + lg * 8);
        }

        f32x4 acc[8] = {};
        #pragma unroll
        for (int kk = 0; kk < 4; ++kk)
            #pragma unroll
            for (int nt = 0; nt < 8; ++nt)
                acc[nt] = __builtin_amdgcn_mfma_f32_16x16x32_bf16(af[kk], bfr[nt][kk], acc[nt], 0, 0, 0);

        #pragma unroll
        for (int nt = 0; nt < 8; ++nt) {
            #pragma unroll
            for (int r = 0; r < 4; ++r) {
                int rr = m0 + lg * 4 + r;
                if (rr < M) {
                    float v = acc[nt][r] + bvals[nt];
                    if (OUTF32) ((float*)Cv)[(size_t)rr * DD + nt * 16 + lr] = v;
                    else ((unsigned short*)Cv)[(size_t)rr * DD + nt * 16 + lr] = f2bf(v);
                }
            }
        }
    }
}

// ---- CSR gather v5: 8 rows/wave, 2-row software pipeline ----
// Per pair: issue 16 row loads + 2 self loads + next pair's 2 chunk loads
// before any wait -> ~80B in flight per wave (vs 32B in v3/v4).
template<int OUTF32, int RELU>
__global__ __launch_bounds__(256) void k_gather8(const int* __restrict__ rowptr, const int2* __restrict__ ev,
                                                 const unsigned* __restrict__ h32, const float* __restrict__ dinv,
                                                 const float* __restrict__ bias, void* __restrict__ outp, int N) {
    int l = threadIdx.x & 63;
    int g = blockIdx.x * 4 + (threadIdx.x >> 6);   // 8-row group id
    int m0 = g * 8;
    if (m0 >= N) return;
    float2 bb = reinterpret_cast<const float2*>(bias)[l];

    // preload 9 row ptrs (lanes 0..8) and 8 dinv (lanes 0..7)
    int rpidx = m0 + l; if (rpidx > N) rpidx = N;
    int rp = (l < 9) ? rowptr[rpidx] : 0;
    int dvidx = m0 + l; if (dvidx >= N) dvidx = N - 1;
    float dv = (l < 8) ? dinv[dvidx] : 0.f;

    // prefetch edge chunks for rows 0,1
    int2 me0, me1;
    {
        int b0 = __builtin_amdgcn_readlane(rp, 0), e0 = __builtin_amdgcn_readlane(rp, 1);
        int c0 = e0 - b0; if (c0 > 64) c0 = 64;
        me0 = (c0 > 0) ? ev[b0 + (l < c0 ? l : c0 - 1)] : make_int2(0, 0);
        int b1 = e0, e1 = __builtin_amdgcn_readlane(rp, 2);
        int c1 = e1 - b1; if (c1 > 64) c1 = 64;
        me1 = (c1 > 0) ? ev[b1 + (l < c1 ? l : c1 - 1)] : make_int2(0, 0);
    }

    #pragma unroll
    for (int r = 0; r < 8; r += 2) {
        int nA = m0 + r, nB = m0 + r + 1;
        int bA = __builtin_amdgcn_readlane(rp, r);
        int eA = __builtin_amdgcn_readlane(rp, r + 1);
        int eB = __builtin_amdgcn_readlane(rp, r + 2);
        int degA = eA - bA, degB = eB - eA;
        int bB = eA;
        int2 mA = me0, mB = me1;
        if (r + 2 < 8) {   // prefetch next pair's chunks (independent loads)
            int b2 = __builtin_amdgcn_readlane(rp, r + 2), e2 = __builtin_amdgcn_readlane(rp, r + 3);
            int c2 = e2 - b2; if (c2 > 64) c2 = 64;
            me0 = (c2 > 0) ? ev[b2 + (l < c2 ? l : c2 - 1)] : make_int2(0, 0);
            int b3 = e2, e3 = __builtin_amdgcn_readlane(rp, r + 4);
            int c3 = e3 - b3; if (c3 > 64) c3 = 64;
            me1 = (c3 > 0) ? ev[b3 + (l < c3 ? l : c3 - 1)] : make_int2(0, 0);
        }

        int cA = degA < 64 ? degA : 64;
        int cB = degB < 64 ? degB : 64;
        int fA = cA < 8 ? cA : 8;
        int fB = cB < 8 ? cB : 8;

        // issue ALL first-round loads for both rows + self rows before any use
        unsigned pA[8], pB[8]; float wA[8], wB[8];
        #pragma unroll
        for (int q = 0; q < 8; ++q) {
            int ia = (q < fA) ? q : (fA > 0 ? fA - 1 : 0);
            int s = __builtin_amdgcn_readlane(mA.x, ia);
            pA[q] = h32[(size_t)s * 64 + l];
            wA[q] = (q < fA) ? rl_f(mA.y, ia) : 0.f;
        }
        #pragma unroll
        for (int q = 0; q < 8; ++q) {
            int ib = (q < fB) ? q : (fB > 0 ? fB - 1 : 0);
            int s = __builtin_amdgcn_readlane(mB.x, ib);
            pB[q] = h32[(size_t)s * 64 + l];
            wB[q] = (q < fB) ? rl_f(mB.y, ib) : 0.f;
        }
        unsigned psA = h32[(size_t)(nA < N ? nA : N - 1) * 64 + l];
        unsigned psB = h32[(size_t)(nB < N ? nB : N - 1) * 64 + l];

        float axA = 0.f, ayA = 0.f, axB = 0.f, ayB = 0.f;
        #pragma unroll
        for (int q = 0; q < 8; ++q) {
            axA = fmaf(wA[q], bflo2f(pA[q]), axA);
            ayA = fmaf(wA[q], bfhi2f(pA[q]), ayA);
            axB = fmaf(wB[q], bflo2f(pB[q]), axB);
            ayB = fmaf(wB[q], bfhi2f(pB[q]), ayB);
        }

        // deg in (8,64]: continue within prefetched chunks
        for (int i = 8; i < cA; i += 8) {
            #pragma unroll
            for (int q = 0; q < 8; ++q) {
                int ia = (i + q < cA) ? i + q : cA - 1;
                int s = __builtin_amdgcn_readlane(mA.x, ia);
                unsigned p = h32[(size_t)s * 64 + l];
                float wq = (i + q < cA) ? rl_f(mA.y, ia) : 0.f;
                axA = fmaf(wq, bflo2f(p), axA);
                ayA = fmaf(wq, bfhi2f(p), ayA);
            }
        }
        for (int i = 8; i < cB; i += 8) {
            #pragma unroll
            for (int q = 0; q < 8; ++q) {
                int ib = (i + q < cB) ? i + q : cB - 1;
                int s = __builtin_amdgcn_readlane(mB.x, ib);
                unsigned p = h32[(size_t)s * 64 + l];
                float wq = (i + q < cB) ? rl_f(mB.y, ib) : 0.f;
                axB = fmaf(wq, bflo2f(p), axB);
                ayB = fmaf(wq, bfhi2f(p), ayB);
            }
        }
        // deg > 64: rare serial tail
        for (int base = 64; base < degA; base += 64) {
            int cc = degA - base; if (cc > 64) cc = 64;
            int2 m2 = ev[bA + base + (l < cc ? l : cc - 1)];
            for (int ii = 0; ii < cc; ++ii) {
                int s = __builtin_amdgcn_readlane(m2.x, ii);
                unsigned p = h32[(size_t)s * 64 + l];
                float wq = rl_f(m2.y, ii);
                axA = fmaf(wq, bflo2f(p), axA);
                ayA = fmaf(wq, bfhi2f(p), ayA);
            }
        }
        for (int base = 64; base < degB; base += 64) {
            int cc = degB - base; if (cc > 64) cc = 64;
            int2 m2 = ev[bB + base + (l < cc ? l : cc - 1)];
            for (int ii = 0; ii < cc; ++ii) {
                int s = __builtin_amdgcn_readlane(m2.x, ii);
                unsigned p = h32[(size_t)s * 64 + l];
                float wq = rl_f(m2.y, ii);
                axB = fmaf(wq, bflo2f(p), axB);
                ayB = fmaf(wq, bfhi2f(p), ayB);
            }
        }

        // epilogue row A
        if (nA < N) {
            float di = __builtin_bit_cast(float, __builtin_amdgcn_readlane(__builtin_bit_cast(int, dv), r));
            float di2 = di * di;
            float ox = fmaf(di2, bflo2f(psA), axA) + bb.x;
            float oy = fmaf(di2, bfhi2f(psA), ayA) + bb.y;
            if (RELU) { ox = fmaxf(ox, 0.f); oy = fmaxf(oy, 0.f); }
            if (OUTF32) reinterpret_cast<float2*>(outp)[(size_t)nA * 64 + l] = make_float2(ox, oy);
            else {
                unsigned po = (unsigned)f2bf(ox) | ((unsigned)f2bf(oy) << 16);
                reinterpret_cast<unsigned*>(outp)[(size_t)nA * 64 + l] = po;
            }
        }
        // epilogue row B
        if (nB < N) {
            float di = __builtin_bit_cast(float, __builtin_amdgcn_readlane(__builtin_bit_cast(int, dv), r + 1));
            float di2 = di * di;
            float ox = fmaf(di2, bflo2f(psB), axB) + bb.x;
            float oy = fmaf(di2, bfhi2f(psB), ayB) + bb.y;
            if (RELU) { ox = fmaxf(ox, 0.f); oy = fmaxf(oy, 0.f); }
            if (OUTF32) reinterpret_cast<float2*>(outp)[(size_t)nB * 64 + l] = make_float2(ox, oy);
            else {
                unsigned po = (unsigned)f2bf(ox) | ((unsigned)f2bf(oy) << 16);
                reinterpret_cast<unsigned*>(outp)[(size_t)nB * 64 + l] = po;
            }
        }
    }
}

extern "C" void kernel_launch(void* const* d_in, const int* in_sizes, int n_in,
                              void* d_out, int out_size, void* d_ws, size_t ws_size,
                              hipStream_t stream) {
    const float* x  = (const float*)d_in[0];
    const int*   ei = (const int*)d_in[1];
    const float* W1 = (const float*)d_in[2];
    const float* b1 = (const float*)d_in[3];
    const float* W2 = (const float*)d_in[4];
    const float* b2 = (const float*)d_in[5];
    // Wq/bq/Wk/bk (6..9) dead: softmax over seq_len=1 is identity.
    const float* Wv = (const float*)d_in[10];
    const float* bv = (const float*)d_in[11];
    const float* Wo = (const float*)d_in[12];
    const float* bo = (const float*)d_in[13];
    int N = in_sizes[0] / DD;
    int E = in_sizes[1] / 2;
    const int* src = ei;
    const int* dst = ei + E;
    float* out = (float*)d_out;

    unsigned* hA  = (unsigned*)d_ws;                  // N*64 u32 (bf16 GEMM out)
    unsigned* h1  = hA + (size_t)N * 64;              // N*64 u32 (bf16 h1)
    float* dinv   = (float*)(h1 + (size_t)N * 64);    // N
    float* Wf     = dinv + N;                         // 128*128 f32
    float* bfo    = Wf + DD * DD;                     // 128
    float* bf2    = bfo + DD;                         // 128
    unsigned short* Wt1  = (unsigned short*)(bf2 + DD);   // 128*128 bf16
    unsigned short* W2ft = Wt1 + DD * DD;                 // 128*128 bf16
    int* cnt    = (int*)(W2ft + DD * DD);             // N
    int* rowptr = cnt + N;                            // N+1
    int* bsums  = rowptr + N + 1;                     // 512
    int2* ev    = (int2*)(((uintptr_t)(bsums + 512) + 15) & ~(uintptr_t)15);  // E

    int nb = (N + 255) / 256;

    // CSR build (shared by both layers)
    hipMemsetAsync(cnt, 0, (size_t)N * sizeof(int), stream);
    k_hist<<<(E + 255) / 256, 256, 0, stream>>>(dst, cnt, E, N);
    k_scan_block<<<nb, 256, 0, stream>>>(cnt, rowptr, bsums, N);
    k_scan_bsums<<<1, 256, 0, stream>>>(bsums, nb);
    k_scan_add<<<nb, 256, 0, stream>>>(rowptr, bsums, cnt, dinv, N);
    k_fill<<<(E + 255) / 256, 256, 0, stream>>>(src, dst, rowptr, cnt, dinv, ev, E, N);

    // weight prep: Wf = Wv@Wo, then {W2f = W2@Wf, Wt1} in one dispatch
    k_fuse1<<<((DD + 1) * DD + 255) / 256, 256, 0, stream>>>(Wv, Wo, bv, bo, Wf, bfo);
    k_wprep<<<129, 256, 0, stream>>>(W2, Wf, b2, bfo, W2ft, bf2, W1, Wt1);

    int gat_blocks = ((N + 7) / 8 + 3) / 4;   // 4 waves/block, 8 rows/wave

    // layer 1: hA = x@W1 ; h1 = relu(G(hA) + b1)
    k_gemm_mfma<1, 0><<<512, 256, 0, stream>>>(x, Wt1, nullptr, hA, N);
    k_gather8<0, 1><<<gat_blocks, 256, 0, stream>>>(rowptr, ev, hA, dinv, b1, h1, N);

    // layer 2 + MHA: hA = h1@(W2·Wv·Wo) ; out = G(hA) + bf2
    k_gemm_mfma<0, 0><<<512, 256, 0, stream>>>(h1, W2ft, nullptr, hA, N);
    k_gather8<1, 0><<<gat_blocks, 256, 0, stream>>>(rowptr, ev, hA, dinv, bf2, out, N);
}

// Round 10
// 187.363 us; speedup vs baseline: 1.4261x; 1.0241x over previous
//
#include <hip/hip_runtime.h>
#include <hip/hip_bf16.h>

#define DD 128

typedef __bf16 bf16x8v __attribute__((ext_vector_type(8)));
typedef float  f32x4   __attribute__((ext_vector_type(4)));

__device__ inline unsigned short f2bf(float f) {
    unsigned u = __builtin_bit_cast(unsigned, f);
    unsigned r = (u + 0x7fffu + ((u >> 16) & 1u)) >> 16;
    return (unsigned short)r;
}
__device__ inline float bflo2f(unsigned p) { return __builtin_bit_cast(float, p << 16); }
__device__ inline float bfhi2f(unsigned p) { return __builtin_bit_cast(float, p & 0xffff0000u); }
__device__ inline float rl_f(int v, int i) {
    return __builtin_bit_cast(float, __builtin_amdgcn_readlane(v, i));
}

// ---- zero cnt + fillc (replaces slow runtime fill kernel) ----
__global__ __launch_bounds__(256) void k_zero(int* __restrict__ a, int* __restrict__ b, int N) {
    int i = blockIdx.x * 256 + threadIdx.x;
    int stride = gridDim.x * 256;
    for (; i < N; i += stride) { a[i] = 0; b[i] = 0; }
}

// ---- hist + fuse1 (Wf = Wv@Wo, bfo = bv@Wo + bo) in one dispatch ----
__global__ __launch_bounds__(256) void k_hist_fuse1(const int* __restrict__ dst, int* __restrict__ cnt,
                                                    int E, int N,
                                                    const float* __restrict__ Wv, const float* __restrict__ Wo,
                                                    const float* __restrict__ bv, const float* __restrict__ bo,
                                                    float* __restrict__ Wf, float* __restrict__ bfo, int EB) {
    if ((int)blockIdx.x < EB) {
        int e = blockIdx.x * 256 + threadIdx.x;
        if (e < E) {
            int d = dst[e];
            if ((unsigned)d < (unsigned)N) atomicAdd(&cnt[d], 1);
        }
    } else {
        int gid = (blockIdx.x - EB) * 256 + threadIdx.x;
        if (gid >= (DD + 1) * DD) return;
        int i = gid >> 7, j = gid & (DD - 1);
        if (i < DD) {
            float acc = 0.f;
            for (int k = 0; k < DD; ++k) acc = fmaf(Wv[i * DD + k], Wo[k * DD + j], acc);
            Wf[i * DD + j] = acc;
        } else {
            float acc = bo[j];
            for (int k = 0; k < DD; ++k) acc = fmaf(bv[k], Wo[k * DD + j], acc);
            bfo[j] = acc;
        }
    }
}

// ---- block scan + weight prep (W2f^T bf16, bf2, Wt1) in one dispatch ----
__global__ __launch_bounds__(256) void k_scanblk_wprep(const int* __restrict__ cnt, int* __restrict__ rowptr,
                                                       int* __restrict__ bsums, int N, int nb,
                                                       const float* __restrict__ W2, const float* __restrict__ Wf,
                                                       const float* __restrict__ b2, const float* __restrict__ bfo,
                                                       unsigned short* __restrict__ W2ft, float* __restrict__ bf2,
                                                       const float* __restrict__ W1, unsigned short* __restrict__ Wt1) {
    if ((int)blockIdx.x < nb) {
        __shared__ int sh[256];
        int t = threadIdx.x;
        int gid = blockIdx.x * 256 + t;
        int v = (gid < N) ? cnt[gid] : 0;
        sh[t] = v;
        __syncthreads();
        #pragma unroll
        for (int off = 1; off < 256; off <<= 1) {
            int add = (t >= off) ? sh[t - off] : 0;
            __syncthreads();
            sh[t] += add;
            __syncthreads();
        }
        if (gid < N) rowptr[gid] = sh[t] - v;
        if (t == 255) bsums[blockIdx.x] = sh[255];
    } else {
        int blk = blockIdx.x - nb;
        if (blk < 65) {
            int gid = blk * 256 + threadIdx.x;
            if (gid >= (DD + 1) * DD) return;
            int i = gid >> 7, j = gid & (DD - 1);
            if (i < DD) {
                float acc = 0.f;
                for (int k = 0; k < DD; ++k) acc = fmaf(W2[i * DD + k], Wf[k * DD + j], acc);
                W2ft[j * DD + i] = f2bf(acc);       // transposed bf16
            } else {
                float acc = bfo[j];
                for (int k = 0; k < DD; ++k) acc = fmaf(b2[k], Wf[k * DD + j], acc);
                bf2[j] = acc;
            }
        } else {
            int gid = (blk - 65) * 256 + threadIdx.x;   // 16384
            int k = gid >> 7, n = gid & 127;
            Wt1[n * DD + k] = f2bf(W1[k * DD + n]);
        }
    }
}

// ---- scan finalize with INLINE bsums scan (each block redundantly scans in LDS) ----
__global__ __launch_bounds__(256) void k_scan_add2(int* __restrict__ rowptr, const int* __restrict__ bsums,
                                                   const int* __restrict__ cnt, float* __restrict__ dinv,
                                                   int N, int nb) {
    __shared__ int sh[512];
    int t = threadIdx.x;
    sh[t]       = (t < nb)       ? bsums[t]       : 0;
    sh[t + 256] = (t + 256 < nb) ? bsums[t + 256] : 0;
    __syncthreads();
    #pragma unroll
    for (int off = 1; off < 512; off <<= 1) {
        int a = (t >= off)       ? sh[t - off]       : 0;
        int b = (t + 256 >= off) ? sh[t + 256 - off] : 0;
        __syncthreads();
        sh[t] += a;
        sh[t + 256] += b;
        __syncthreads();
    }
    int b = blockIdx.x;
    int pfx = (b == 0) ? 0 : sh[b - 1];
    int gid = b * 256 + t;
    if (gid < N) {
        int c = cnt[gid];
        int v = rowptr[gid] + pfx;
        rowptr[gid] = v;
        if (gid == N - 1) rowptr[N] = v + c;
        dinv[gid] = rsqrtf(1.0f + (float)c);
    }
}

// ---- fill CSR + layer-1 MFMA GEMM in one dispatch (independent work) ----
// fill: blocks [0, EB) ; gemm: blocks [EB, EB+512), persistent over tiles.
__global__ __launch_bounds__(256, 2) void k_fill_gemm1(const int* __restrict__ src, const int* __restrict__ dst,
                                                       const int* __restrict__ rowptr, int* __restrict__ fillc,
                                                       const float* __restrict__ dinv, int2* __restrict__ ev,
                                                       int E, int N, int EB,
                                                       const float* __restrict__ Af,
                                                       const unsigned short* __restrict__ Wt,
                                                       unsigned short* __restrict__ Cb) {
    if ((int)blockIdx.x < EB) {
        int e = blockIdx.x * 256 + threadIdx.x;
        if (e >= E) return;
        int s = src[e], d = dst[e];
        if ((unsigned)s >= (unsigned)N || (unsigned)d >= (unsigned)N) return;
        int pos = rowptr[d] + atomicAdd(&fillc[d], 1);
        float nm = dinv[s] * dinv[d];
        ev[pos] = make_int2(s, __builtin_bit_cast(int, nm));
        return;
    }
    // ---- GEMM part: Cb[M x 128] bf16 = bf16(Af[M x 128] f32) @ Wt^T ----
    int w  = threadIdx.x >> 6;
    int l  = threadIdx.x & 63;
    int lr = l & 15, lg = l >> 4;

    bf16x8v bfr[8][4];
    #pragma unroll
    for (int nt = 0; nt < 8; ++nt)
        #pragma unroll
        for (int kk = 0; kk < 4; ++kk)
            bfr[nt][kk] = *reinterpret_cast<const bf16x8v*>(Wt + (nt * 16 + lr) * DD + kk * 32 + lg * 8);

    int tiles = (N + 63) >> 6;
    for (int t = blockIdx.x - EB; t < tiles; t += 512) {
        int m0 = t * 64 + w * 16;
        int row = m0 + lr;
        int rowc = row < N ? row : (N - 1);

        bf16x8v af[4];
        #pragma unroll
        for (int kk = 0; kk < 4; ++kk) {
            const float* p = Af + (size_t)rowc * DD + kk * 32 + lg * 8;
            float4 u0 = *reinterpret_cast<const float4*>(p);
            float4 u1 = *reinterpret_cast<const float4*>(p + 4);
            af[kk][0] = (__bf16)u0.x; af[kk][1] = (__bf16)u0.y;
            af[kk][2] = (__bf16)u0.z; af[kk][3] = (__bf16)u0.w;
            af[kk][4] = (__bf16)u1.x; af[kk][5] = (__bf16)u1.y;
            af[kk][6] = (__bf16)u1.z; af[kk][7] = (__bf16)u1.w;
        }

        f32x4 acc[8] = {};
        #pragma unroll
        for (int kk = 0; kk < 4; ++kk)
            #pragma unroll
            for (int nt = 0; nt < 8; ++nt)
                acc[nt] = __builtin_amdgcn_mfma_f32_16x16x32_bf16(af[kk], bfr[nt][kk], acc[nt], 0, 0, 0);

        #pragma unroll
        for (int nt = 0; nt < 8; ++nt)
            #pragma unroll
            for (int r = 0; r < 4; ++r) {
                int rr = m0 + lg * 4 + r;
                if (rr < N) Cb[(size_t)rr * DD + nt * 16 + lr] = f2bf(acc[nt][r]);
            }
    }
}

// ---- MFMA GEMM (bf16 in, bf16 out): layer 2 ----
__global__ __launch_bounds__(256, 2) void k_gemm_mfma(const unsigned short* __restrict__ Ab,
                                                      const unsigned short* __restrict__ Wt,
                                                      unsigned short* __restrict__ Cb, int M) {
    int w  = threadIdx.x >> 6;
    int l  = threadIdx.x & 63;
    int lr = l & 15, lg = l >> 4;

    bf16x8v bfr[8][4];
    #pragma unroll
    for (int nt = 0; nt < 8; ++nt)
        #pragma unroll
        for (int kk = 0; kk < 4; ++kk)
            bfr[nt][kk] = *reinterpret_cast<const bf16x8v*>(Wt + (nt * 16 + lr) * DD + kk * 32 + lg * 8);

    int tiles = (M + 63) >> 6;
    for (int t = blockIdx.x; t < tiles; t += gridDim.x) {
        int m0 = t * 64 + w * 16;
        int row = m0 + lr;
        int rowc = row < M ? row : (M - 1);

        bf16x8v af[4];
        #pragma unroll
        for (int kk = 0; kk < 4; ++kk)
            af[kk] = *reinterpret_cast<const bf16x8v*>(Ab + (size_t)rowc * DD + kk * 32 + lg * 8);

        f32x4 acc[8] = {};
        #pragma unroll
        for (int kk = 0; kk < 4; ++kk)
            #pragma unroll
            for (int nt = 0; nt < 8; ++nt)
                acc[nt] = __builtin_amdgcn_mfma_f32_16x16x32_bf16(af[kk], bfr[nt][kk], acc[nt], 0, 0, 0);

        #pragma unroll
        for (int nt = 0; nt < 8; ++nt)
            #pragma unroll
            for (int r = 0; r < 4; ++r) {
                int rr = m0 + lg * 4 + r;
                if (rr < M) Cb[(size_t)rr * DD + nt * 16 + lr] = f2bf(acc[nt][r]);
            }
    }
}

// ---- CSR gather v6: half-split. Lanes 0-31 = row A, 32-63 = row B. ----
// Each lane loads uint2 (4 features); one load instr gathers for TWO rows.
// 8 rows/wave as 4 pairs, chunk prefetched one pair ahead.
template<int OUTF32, int RELU>
__global__ __launch_bounds__(256) void k_gather_hs(const int* __restrict__ rowptr, const int2* __restrict__ ev,
                                                   const uint2* __restrict__ h2, const float* __restrict__ dinv,
                                                   const float* __restrict__ bias, void* __restrict__ outp,
                                                   int N, int E) {
    int l = threadIdx.x & 63;
    int wv = blockIdx.x * 4 + (threadIdx.x >> 6);
    int m0 = wv * 8;
    if (m0 >= N) return;
    int hh = l >> 5;          // 0: row A, 1: row B
    int q  = l & 31;
    float4 bb = reinterpret_cast<const float4*>(bias)[q];

    // preload 9 rowptrs (lanes 0..8), 8 dinv (lanes 0..7)
    int rpidx = m0 + l; if (rpidx > N) rpidx = N;
    int rp = (l < 9) ? rowptr[rpidx] : 0;
    int dvidx = m0 + l; if (dvidx >= N) dvidx = N - 1;
    float dv = (l < 8) ? dinv[dvidx] : 0.f;

    // prefetch chunk for pair 0: lanes 0-31 row A edges, 32-63 row B edges
    int2 me;
    {
        int bA = __builtin_amdgcn_readlane(rp, 0);
        int eA = __builtin_amdgcn_readlane(rp, 1);
        int eB = __builtin_amdgcn_readlane(rp, 2);
        int cA = eA - bA; if (cA > 32) cA = 32;
        int cB = eB - eA; if (cB > 32) cB = 32;
        int iA = bA + (q < cA ? q : (cA > 0 ? cA - 1 : 0)); if (iA >= E) iA = E - 1;
        int iB = eA + (q < cB ? q : (cB > 0 ? cB - 1 : 0)); if (iB >= E) iB = E - 1;
        me = ev[hh ? iB : iA];
    }

    #pragma unroll
    for (int t = 0; t < 4; ++t) {
        int nA = m0 + 2 * t, nB = nA + 1;
        int bA = __builtin_amdgcn_readlane(rp, 2 * t);
        int eA = __builtin_amdgcn_readlane(rp, 2 * t + 1);
        int eB = __builtin_amdgcn_readlane(rp, 2 * t + 2);
        int degA = eA - bA, degB = eB - eA;
        int cA = degA < 32 ? degA : 32;
        int cB = degB < 32 ? degB : 32;
        int2 mc = me;
        if (t < 3) {   // prefetch next pair's chunk
            int bA2 = __builtin_amdgcn_readlane(rp, 2 * t + 2);
            int eA2 = __builtin_amdgcn_readlane(rp, 2 * t + 3);
            int eB2 = __builtin_amdgcn_readlane(rp, 2 * t + 4);
            int cA2 = eA2 - bA2; if (cA2 > 32) cA2 = 32;
            int cB2 = eB2 - eA2; if (cB2 > 32) cB2 = 32;
            int iA = bA2 + (q < cA2 ? q : (cA2 > 0 ? cA2 - 1 : 0)); if (iA >= E) iA = E - 1;
            int iB = eA2 + (q < cB2 ? q : (cB2 > 0 ? cB2 - 1 : 0)); if (iB >= E) iB = E - 1;
            me = ev[hh ? iB : iA];
        }

        float a0 = 0.f, a1 = 0.f, a2 = 0.f, a3 = 0.f;
        int cmax = cA > cB ? cA : cB;
        for (int i = 0; i < cmax; i += 8) {
            uint2 p[8]; float w[8];
            #pragma unroll
            for (int j = 0; j < 8; ++j) {
                int jA = i + j; if (jA >= cA) jA = cA - 1; if (jA < 0) jA = 0;
                int jB = i + j; if (jB >= cB) jB = cB - 1; if (jB < 0) jB = 0;
                int sA = __builtin_amdgcn_readlane(mc.x, jA);
                int sB = __builtin_amdgcn_readlane(mc.x, 32 + jB);
                float wA = rl_f(mc.y, jA);
                float wB = rl_f(mc.y, 32 + jB);
                int s  = hh ? sB : sA;
                int cc = hh ? cB : cA;
                p[j] = h2[(size_t)s * 32 + q];
                w[j] = (i + j < cc) ? (hh ? wB : wA) : 0.f;
            }
            #pragma unroll
            for (int j = 0; j < 8; ++j) {
                a0 = fmaf(w[j], bflo2f(p[j].x), a0);
                a1 = fmaf(w[j], bfhi2f(p[j].x), a1);
                a2 = fmaf(w[j], bflo2f(p[j].y), a2);
                a3 = fmaf(w[j], bfhi2f(p[j].y), a3);
            }
        }
        // rare tail: deg > 32
        int degmax = degA > degB ? degA : degB;
        for (int base = 32; base < degmax; base += 32) {
            int c2A = degA - base; if (c2A > 32) c2A = 32;
            int c2B = degB - base; if (c2B > 32) c2B = 32;
            int iA = bA + base + (q < c2A ? q : (c2A > 0 ? c2A - 1 : 0));
            if (iA >= E) iA = E - 1; if (iA < bA) iA = bA;
            int iB = eA + base + (q < c2B ? q : (c2B > 0 ? c2B - 1 : 0));
            if (iB >= E) iB = E - 1; if (iB < eA) iB = eA;
            int2 m2 = ev[hh ? iB : iA];
            int c2m = c2A > c2B ? c2A : c2B;
            for (int j = 0; j < c2m; ++j) {
                int jA = j; if (jA >= c2A) jA = c2A > 0 ? c2A - 1 : 0;
                int jB = j; if (jB >= c2B) jB = c2B > 0 ? c2B - 1 : 0;
                int sA = __builtin_amdgcn_readlane(m2.x, jA);
                int sB = __builtin_amdgcn_readlane(m2.x, 32 + jB);
                float wA = rl_f(m2.y, jA);
                float wB = rl_f(m2.y, 32 + jB);
                int s  = hh ? sB : sA;
                int cc = hh ? c2B : c2A;
                uint2 pp = h2[(size_t)s * 32 + q];
                float wq = (j < cc) ? (hh ? wB : wA) : 0.f;
                a0 = fmaf(wq, bflo2f(pp.x), a0);
                a1 = fmaf(wq, bfhi2f(pp.x), a1);
                a2 = fmaf(wq, bflo2f(pp.y), a2);
                a3 = fmaf(wq, bfhi2f(pp.y), a3);
            }
        }

        // self loop + bias + activation + write
        int nS = hh ? nB : nA;
        int nSc = nS < N ? nS : N - 1;
        uint2 ps = h2[(size_t)nSc * 32 + q];
        float diA = __builtin_bit_cast(float, __builtin_amdgcn_readlane(__builtin_bit_cast(int, dv), 2 * t));
        float diB = __builtin_bit_cast(float, __builtin_amdgcn_readlane(__builtin_bit_cast(int, dv), 2 * t + 1));
        float di = hh ? diB : diA;
        float di2 = di * di;
        a0 = fmaf(di2, bflo2f(ps.x), a0) + bb.x;
        a1 = fmaf(di2, bfhi2f(ps.x), a1) + bb.y;
        a2 = fmaf(di2, bflo2f(ps.y), a2) + bb.z;
        a3 = fmaf(di2, bfhi2f(ps.y), a3) + bb.w;
        if (RELU) {
            a0 = fmaxf(a0, 0.f); a1 = fmaxf(a1, 0.f);
            a2 = fmaxf(a2, 0.f); a3 = fmaxf(a3, 0.f);
        }
        if (nS < N) {
            if (OUTF32) {
                reinterpret_cast<float4*>(outp)[(size_t)nS * 32 + q] = make_float4(a0, a1, a2, a3);
            } else {
                uint2 po;
                po.x = (unsigned)f2bf(a0) | ((unsigned)f2bf(a1) << 16);
                po.y = (unsigned)f2bf(a2) | ((unsigned)f2bf(a3) << 16);
                reinterpret_cast<uint2*>(outp)[(size_t)nS * 32 + q] = po;
            }
        }
    }
}

extern "C" void kernel_launch(void* const* d_in, const int* in_sizes, int n_in,
                              void* d_out, int out_size, void* d_ws, size_t ws_size,
                              hipStream_t stream) {
    const float* x  = (const float*)d_in[0];
    const int*   ei = (const int*)d_in[1];
    const float* W1 = (const float*)d_in[2];
    const float* b1 = (const float*)d_in[3];
    const float* W2 = (const float*)d_in[4];
    const float* b2 = (const float*)d_in[5];
    // Wq/bq/Wk/bk (6..9) dead: softmax over seq_len=1 is identity.
    const float* Wv = (const float*)d_in[10];
    const float* bv = (const float*)d_in[11];
    const float* Wo = (const float*)d_in[12];
    const float* bo = (const float*)d_in[13];
    int N = in_sizes[0] / DD;
    int E = in_sizes[1] / 2;
    const int* src = ei;
    const int* dst = ei + E;
    float* out = (float*)d_out;

    unsigned* hA  = (unsigned*)d_ws;                  // N*64 u32 (bf16 GEMM out)
    unsigned* h1  = hA + (size_t)N * 64;              // N*64 u32 (bf16 h1)
    float* dinv   = (float*)(h1 + (size_t)N * 64);    // N
    float* Wf     = dinv + N;                         // 128*128 f32
    float* bfo    = Wf + DD * DD;                     // 128
    float* bf2    = bfo + DD;                         // 128
    unsigned short* Wt1  = (unsigned short*)(bf2 + DD);   // 128*128 bf16
    unsigned short* W2ft = Wt1 + DD * DD;                 // 128*128 bf16
    int* cnt    = (int*)(W2ft + DD * DD);             // N
    int* fillc  = cnt + N;                            // N
    int* rowptr = fillc + N;                          // N+1
    int* bsums  = rowptr + N + 1;                     // 512
    int2* ev    = (int2*)(((uintptr_t)(bsums + 512) + 15) & ~(uintptr_t)15);  // E

    int nb = (N + 255) / 256;
    int EB = (E + 255) / 256;

    // D1: zero counters
    k_zero<<<512, 256, 0, stream>>>(cnt, fillc, N);
    // D2: degree histogram + MHA weight fold (independent block ranges)
    k_hist_fuse1<<<EB + 129, 256, 0, stream>>>(dst, cnt, E, N, Wv, Wo, bv, bo, Wf, bfo, EB);
    // D3: block-level scan + weight transposes (needs Wf from D2)
    k_scanblk_wprep<<<nb + 129, 256, 0, stream>>>(cnt, rowptr, bsums, N, nb,
                                                  W2, Wf, b2, bfo, W2ft, bf2, W1, Wt1);
    // D4: scan finalize (inline bsums scan) + dinv
    k_scan_add2<<<nb, 256, 0, stream>>>(rowptr, bsums, cnt, dinv, N, nb);
    // D5: CSR fill + layer-1 GEMM (independent block ranges)
    k_fill_gemm1<<<EB + 512, 256, 0, stream>>>(src, dst, rowptr, fillc, dinv, ev, E, N, EB,
                                               x, Wt1, (unsigned short*)hA);
    int gb = ((N + 7) / 8 + 3) / 4;   // 4 waves/block, 8 rows/wave
    // D6: gather layer 1 -> h1 (bf16, relu)
    k_gather_hs<0, 1><<<gb, 256, 0, stream>>>(rowptr, ev, (const uint2*)hA, dinv, b1, h1, N, E);
    // D7: layer-2 GEMM (W2·Wv·Wo folded)
    k_gemm_mfma<<<512, 256, 0, stream>>>((const unsigned short*)h1, W2ft, (unsigned short*)hA, N);
    // D8: gather layer 2 -> out (f32, +bf2 bias)
    k_gather_hs<1, 0><<<gb, 256, 0, stream>>>(rowptr, ev, (const uint2*)hA, dinv, bf2, out, N, E);
}